// Round 2
// baseline (40.541 us; speedup 1.0000x reference)
//
#include <hip/hip_runtime.h>
#include <stdint.h>

typedef unsigned short u16;
typedef __attribute__((ext_vector_type(4))) u16    u16x4;
typedef __attribute__((ext_vector_type(8))) u16    u16x8;
typedef __attribute__((ext_vector_type(4))) float  f32x4;
typedef __attribute__((ext_vector_type(8))) __bf16 bf16x8;

__device__ __forceinline__ u16 f2bf(float f) {
    union { float f; uint32_t u; } v; v.f = f;
    uint32_t u = v.u;
    uint32_t rb = 0x7FFFu + ((u >> 16) & 1u);
    return (u16)((u + rb) >> 16);
}

// ---------------- kernel 0: W[k][f] -> Wt[f][k] bf16 ----------------
__global__ __launch_bounds__(256) void gcn_wt(const float* __restrict__ W,
                                              u16* __restrict__ Wt) {
    int idx = blockIdx.x * 256 + threadIdx.x;   // 0..16383
    int k = idx >> 7, f = idx & 127;
    Wt[f * 128 + k] = f2bf(W[idx]);
}

// ---------------- kernel 1: hT[b][f][n] = bf16((x@W)^T + b) ----------------
// grid 256: block = (batch b, n-block of 128). LDS: Wt tile + x tile, swizzled.
__global__ __launch_bounds__(256) void gcn_xw(const float* __restrict__ x,
                                              const u16* __restrict__ Wt,
                                              const float* __restrict__ bias,
                                              u16* __restrict__ hT) {
    __shared__ u16 Wl[128 * 128];   // [f][k] swizzled (256B rows)
    __shared__ u16 Xl[128 * 128];   // [n][k] swizzled (256B rows)
    const int t  = threadIdx.x;
    const int bb = blockIdx.x >> 3;
    const int n0 = (blockIdx.x & 7) << 7;

    // stage Wt (already bf16): 16384 u16 = 4096 8B-chunks, 16 per thread
#pragma unroll
    for (int i = 0; i < 16; ++i) {
        int o  = i * 256 + t;          // 8B chunk index, 0..4095
        int f  = o >> 5;               // 32 chunks per 256B row
        int kb = (o & 31) * 8;         // byte in row
        u16x4 v = *(const u16x4*)((const char*)Wt + o * 8);
        *(u16x4*)((char*)Wl + f * 256 + (kb ^ ((f & 7) << 4))) = v;
    }
    // stage x tile [128n][128k] fp32 -> bf16
    const float* xb = x + (size_t)bb * (1024 * 128) + (size_t)n0 * 128;
#pragma unroll
    for (int i = 0; i < 16; ++i) {
        int o4 = i * 256 + t;          // float4 index, 0..4095
        int n  = o4 >> 5;              // 32 float4 per row
        int kb = (o4 & 31) * 8;        // byte offset in bf16 row
        f32x4 v = *(const f32x4*)(xb + (size_t)o4 * 4);
        u16x4 h; h.x = f2bf(v.x); h.y = f2bf(v.y); h.z = f2bf(v.z); h.w = f2bf(v.w);
        *(u16x4*)((char*)Xl + n * 256 + (kb ^ ((n & 7) << 4))) = h;
    }
    __syncthreads();

    const int w = t >> 6, l = t & 63;
    const int wr = w >> 1, wc = w & 1;     // wave quadrant: 64f x 64n
    f32x4 acc[4][4] = {};
#pragma unroll
    for (int kk = 0; kk < 4; ++kk) {
        const int kbyte = kk * 64 + (l >> 4) * 16;
        bf16x8 a[4], b[4];
#pragma unroll
        for (int mf = 0; mf < 4; ++mf) {
            int fl = wr * 64 + mf * 16 + (l & 15);
            a[mf] = *(const bf16x8*)((const char*)Wl + fl * 256 + (kbyte ^ ((fl & 7) << 4)));
        }
#pragma unroll
        for (int nn = 0; nn < 4; ++nn) {
            int nl = wc * 64 + nn * 16 + (l & 15);
            b[nn] = *(const bf16x8*)((const char*)Xl + nl * 256 + (kbyte ^ ((nl & 7) << 4)));
        }
#pragma unroll
        for (int mf = 0; mf < 4; ++mf)
#pragma unroll
            for (int nn = 0; nn < 4; ++nn)
                acc[mf][nn] = __builtin_amdgcn_mfma_f32_16x16x32_bf16(
                    a[mf], b[nn], acc[mf][nn], 0, 0, 0);
    }

    u16* ho = hT + (size_t)bb * 131072;
#pragma unroll
    for (int mf = 0; mf < 4; ++mf) {
        int fbase = wr * 64 + mf * 16 + (l >> 4) * 4;
#pragma unroll
        for (int r = 0; r < 4; ++r) {
            float bv = bias[fbase + r];
#pragma unroll
            for (int nn = 0; nn < 4; ++nn) {
                int n = wc * 64 + nn * 16 + (l & 15);
                ho[(size_t)(fbase + r) * 1024 + n0 + n] = f2bf(acc[mf][nn][r] + bv);
            }
        }
    }
}

// ---------------- kernel 2: out = relu(adj @ h + x) ----------------
// grid 512: (batch, 64-row block), XCD-swizzled. BM=64, BN=128, BK=64.
__global__ __launch_bounds__(256) void gcn_agg(const float* __restrict__ adj,
                                               const u16* __restrict__ hT,
                                               const float* __restrict__ x,
                                               float* __restrict__ out) {
    __shared__ u16 Al[64 * 64];     // adj tile [r][k] bf16, swizzled (128B rows)
    __shared__ u16 Bl[128 * 64];    // hT tile [f][k] bf16, swizzled (128B rows)

    const int t = threadIdx.x;
    // bijective XCD swizzle: 512 blocks, 64 per XCD; one XCD owns 4 whole batches
    const int L  = (blockIdx.x & 7) * 64 + (blockIdx.x >> 3);
    const int bb = L >> 4;
    const int r0 = (L & 15) << 6;

    const float* adjb = adj + (size_t)bb * 1024 * 1024 + (size_t)r0 * 1024;
    const u16*   hTb  = hT + (size_t)bb * 131072;

    const int w = t >> 6, l = t & 63;
    const int wr = w >> 1, wc = w & 1;      // wave: 32 rows x 64 f
    f32x4 acc[2][4] = {};

    // register prefetch buffers (tile ks+1 loaded while computing ks)
    f32x4 aReg[4];
    u16x8 bReg[4];
#pragma unroll
    for (int i = 0; i < 4; ++i) {
        int o4 = i * 256 + t;
        aReg[i] = *(const f32x4*)(adjb + (size_t)(o4 >> 4) * 1024 + (o4 & 15) * 4);
        int o16 = i * 256 + t;
        bReg[i] = *(const u16x8*)((const char*)(hTb + (size_t)(o16 >> 3) * 1024) + (o16 & 7) * 16);
    }

    for (int ks = 0; ks < 16; ++ks) {
        if (ks) __syncthreads();             // prev compute done reading LDS
        // write prefetched regs -> LDS (fp32->bf16 for A)
#pragma unroll
        for (int i = 0; i < 4; ++i) {
            int o4 = i * 256 + t;
            int r = o4 >> 4, kb = (o4 & 15) * 8;
            u16x4 h; h.x = f2bf(aReg[i].x); h.y = f2bf(aReg[i].y);
            h.z = f2bf(aReg[i].z); h.w = f2bf(aReg[i].w);
            *(u16x4*)((char*)Al + r * 128 + (kb ^ ((r & 7) << 4))) = h;
            int o16 = i * 256 + t;
            int f = o16 >> 3, kb2 = (o16 & 7) * 16;
            *(u16x8*)((char*)Bl + f * 128 + (kb2 ^ ((f & 7) << 4))) = bReg[i];
        }
        __syncthreads();

        // issue next tile's global loads (hidden under MFMA below)
        if (ks + 1 < 16) {
            int k0n = (ks + 1) * 64;
#pragma unroll
            for (int i = 0; i < 4; ++i) {
                int o4 = i * 256 + t;
                aReg[i] = *(const f32x4*)(adjb + (size_t)(o4 >> 4) * 1024 + k0n + (o4 & 15) * 4);
                int o16 = i * 256 + t;
                bReg[i] = *(const u16x8*)((const char*)(hTb + (size_t)(o16 >> 3) * 1024 + k0n) + (o16 & 7) * 16);
            }
        }

#pragma unroll
        for (int kk = 0; kk < 2; ++kk) {
            const int kbyte = kk * 64 + (l >> 4) * 16;
            bf16x8 a[2], b[4];
#pragma unroll
            for (int mf = 0; mf < 2; ++mf) {
                int rl = wr * 32 + mf * 16 + (l & 15);
                a[mf] = *(const bf16x8*)((const char*)Al + rl * 128 + (kbyte ^ ((rl & 7) << 4)));
            }
#pragma unroll
            for (int nn = 0; nn < 4; ++nn) {
                int fl = wc * 64 + nn * 16 + (l & 15);
                b[nn] = *(const bf16x8*)((const char*)Bl + fl * 128 + (kbyte ^ ((fl & 7) << 4)));
            }
#pragma unroll
            for (int mf = 0; mf < 2; ++mf)
#pragma unroll
                for (int nn = 0; nn < 4; ++nn)
                    acc[mf][nn] = __builtin_amdgcn_mfma_f32_16x16x32_bf16(
                        a[mf], b[nn], acc[mf][nn], 0, 0, 0);
        }
    }

    // epilogue: + x, relu, fp32 store
    const float* xb = x + (size_t)bb * 131072;
    float*       ob = out + (size_t)bb * 131072;
#pragma unroll
    for (int mf = 0; mf < 2; ++mf) {
#pragma unroll
        for (int j = 0; j < 4; ++j) {
            int r = r0 + wr * 32 + mf * 16 + (l >> 4) * 4 + j;
#pragma unroll
            for (int nn = 0; nn < 4; ++nn) {
                int f = wc * 64 + nn * 16 + (l & 15);
                size_t idx = (size_t)r * 128 + f;
                float v = acc[mf][nn][j] + xb[idx];
                ob[idx] = fmaxf(v, 0.0f);
            }
        }
    }
}

extern "C" void kernel_launch(void* const* d_in, const int* in_sizes, int n_in,
                              void* d_out, int out_size, void* d_ws, size_t ws_size,
                              hipStream_t stream) {
    const float* x    = (const float*)d_in[0];
    const float* adj  = (const float*)d_in[1];
    const float* W    = (const float*)d_in[2];
    const float* bias = (const float*)d_in[3];
    float* out = (float*)d_out;

    u16* hT = (u16*)d_ws;                                   // 32*128*1024*2 = 8 MiB
    u16* Wt = (u16*)((char*)d_ws + (size_t)32 * 131072 * 2); // +32 KiB

    gcn_wt <<<dim3(64),  dim3(256), 0, stream>>>(W, Wt);
    gcn_xw <<<dim3(256), dim3(256), 0, stream>>>(x, Wt, bias, hT);
    gcn_agg<<<dim3(512), dim3(256), 0, stream>>>(adj, hT, x, out);
}